// Round 17
// baseline (17.752 us; speedup 1.0000x reference)
//
#include <hip/hip_runtime.h>

typedef short s16x8 __attribute__((ext_vector_type(8)));
typedef float f32x4 __attribute__((ext_vector_type(4)));
typedef int i32x4 __attribute__((ext_vector_type(4)));

__device__ __forceinline__ short f2bf(float f) {  // RNE f32->bf16
  union { float f; unsigned u; } cv;
  cv.f = f;
  unsigned u = cv.u;
  u = (u + 0x7FFFu + ((u >> 16) & 1u)) >> 16;
  return (short)u;
}
// pack two f32 -> bf16x2 by truncation (low elem = lo)
__device__ __forceinline__ unsigned pk2(float lo, float hi) {
  union { float f; unsigned u; } a, b;
  a.f = lo;
  b.f = hi;
  return (a.u >> 16) | (b.u & 0xFFFF0000u);
}

// ---------------------------------------------------------------------------
// K1 (r16-proven, verbatim): blocks 0..19 = McT table; blocks 20..531 =
// histogram (b, row-half), contiguous nt reads, partial counts -> cnt_h.
// ---------------------------------------------------------------------------
__global__ __launch_bounds__(256, 4) void hist_mc_kernel(
    const int* __restrict__ bfm, const float* __restrict__ adj_w,
    const float* __restrict__ adj_a, uint2* __restrict__ cnt_h,
    unsigned short* __restrict__ McT) {
  __shared__ unsigned red[4][32][4][2];
  __shared__ float As[5][128];
  const int t = threadIdx.x;

  if (blockIdx.x < 20) {  // ---- McT blocks ----
    const int bi = blockIdx.x;
    const int e = bi >> 2, mg = bi & 3;
    for (int idx = t; idx < 640; idx += 256) As[idx >> 7][idx & 127] = adj_a[idx];
    __syncthreads();
    const int m = mg * 32 + (t >> 3), ns = t & 7;
    const float* W = adj_w + (size_t)e * 16384 + (size_t)m * 128 + ns * 16;
    float acc[5] = {0.f, 0.f, 0.f, 0.f, 0.f};
#pragma unroll
    for (int it = 0; it < 4; ++it) {
      const float4 wv = *(const float4*)(W + it * 4);
      const float wa[4] = {wv.x, wv.y, wv.z, wv.w};
#pragma unroll
      for (int q = 0; q < 4; ++q) {
        const int n = ns * 16 + it * 4 + q;
#pragma unroll
        for (int a = 0; a < 5; ++a) acc[a] = fmaf(wa[q], As[a][n], acc[a]);
      }
    }
#pragma unroll
    for (int d = 1; d < 8; d <<= 1)
#pragma unroll
      for (int a = 0; a < 5; ++a) acc[a] += __shfl_xor(acc[a], d);
    if (ns == 0) {
#pragma unroll
      for (int a = 0; a < 5; ++a)
        McT[m * 40 + e * 5 + a] = (unsigned short)f2bf(acc[a]);
      if (e == 0)
#pragma unroll
        for (int r = 25; r < 40; ++r) McT[m * 40 + r] = 0;
    }
    return;
  }

  // ---- hist blocks: contiguous 1KB-per-wave nontemporal reads ----
  const int idx2 = blockIdx.x - 20;
  const int b = idx2 >> 1, hh = idx2 & 1;
  const int w = t >> 6, l = t & 63;
  const i32x4* bp = (const i32x4*)bfm + (size_t)b * 4096 + hh * 2048;
  unsigned pA[4] = {0, 0, 0, 0}, pB[4] = {0, 0, 0, 0};
#pragma unroll
  for (int it = 0; it < 8; ++it) {
    const i32x4 v = __builtin_nontemporal_load(&bp[it * 256 + t]);
#pragma unroll
    for (int jj = 0; jj < 4; ++jj) {
      const int vj = v[jj];
      pA[jj] += (unsigned)(vj == 1) + ((unsigned)(vj == 2) << 8) +
                ((unsigned)(vj == 3) << 16) + ((unsigned)(vj == 4) << 24);
      pB[jj] += (unsigned)(vj == 5);
    }
  }
#pragma unroll
  for (int jj = 0; jj < 4; ++jj) {  // lanes l and l^32 share columns
    pA[jj] += (unsigned)__shfl_xor((int)pA[jj], 32);
    pB[jj] += (unsigned)__shfl_xor((int)pB[jj], 32);
  }
  if (l < 32) {
#pragma unroll
    for (int jj = 0; jj < 4; ++jj) {
      red[w][l][jj][0] = pA[jj];
      red[w][l][jj][1] = pB[jj];
    }
  }
  __syncthreads();
  if (t < 128) {
    unsigned A = 0, B = 0;
    const int cc = t >> 2, jj = t & 3;
#pragma unroll
    for (int w2 = 0; w2 < 4; ++w2) {
      A += red[w2][cc][jj][0];
      B += red[w2][cc][jj][1];
    }
    cnt_h[(b * 2 + hh) * 128 + t] = make_uint2(A, B);  // bytes <= 64
  }
}

// ---------------------------------------------------------------------------
// K2: out[b, qq*32 .. +32, :] = (adj@P) @ McT, two skinny MFMA stages.
// 1024 blocks (b, quarter) x 128 threads (2 waves x 16 rows), 20.5 KB LDS
// -> 4 blocks/CU co-resident: compute phases of some blocks overlap the
// stream phases of others (burst smoothing). nt loads/stores as r16.
// ---------------------------------------------------------------------------
__global__ __launch_bounds__(128, 2) void skinny_kernel(
    const float* __restrict__ adj, const int* __restrict__ a_bfm,
    const uint2* __restrict__ cnt_h, const unsigned short* __restrict__ McT,
    float* __restrict__ out) {
  __shared__ __align__(16) unsigned short Pt[32 * 128];     // 8 KB, XOR-swz
  __shared__ __align__(16) unsigned short Mt[128 * 40];     // 10 KB
  __shared__ __align__(16) unsigned short Qs[2 * 16 * 40];  // 2.5 KB
  const int bq = blockIdx.x, b = bq >> 2, qq = bq & 3;
  const int t = threadIdx.x, w = t >> 6, l = t & 63, g = l >> 4, c = l & 15;
  const int row0 = qq * 32 + w * 16;

  // ---- T0: small loads first (consumed first), adj last (consumed last) ----
  const uint2 h0 = cnt_h[(b * 2 + 0) * 128 + t];
  const uint2 h1 = cnt_h[(b * 2 + 1) * 128 + t];
  const int av = a_bfm[b * 128 + t];
  s16x8 mst[5];
#pragma unroll
  for (int i = 0; i < 5; ++i) mst[i] = *(const s16x8*)&McT[(i * 128 + t) * 8];
  const float* arow = adj + (size_t)b * 16384 + (size_t)(row0 + c) * 128;
  f32x4 a0[4], a1[4];
#pragma unroll
  for (int kk = 0; kk < 4; ++kk) {
    a0[kk] = __builtin_nontemporal_load((const f32x4*)(arow + kk * 32 + g * 8));
    a1[kk] =
        __builtin_nontemporal_load((const f32x4*)(arow + kk * 32 + g * 8 + 4));
  }

  // ---- zero Pt; stage Mt (vmcnt waits only to mst; adj stays queued) ----
#pragma unroll
  for (int i = 0; i < 4; ++i)
    ((uint4*)Pt)[i * 128 + t] = make_uint4(0u, 0u, 0u, 0u);
#pragma unroll
  for (int i = 0; i < 5; ++i) *(s16x8*)&Mt[(i * 128 + t) * 8] = mst[i];
  asm volatile("s_waitcnt lgkmcnt(0)" ::: "memory");
  __builtin_amdgcn_s_barrier();

  // ---- scatter P^T: Pt[r][j=t] = cnt_e(j), r=(e-1)*5+ai, XOR-swz chunks ----
  if (av > 0) {
    const unsigned cx = h0.x + h1.x;  // byte-packed add, bytes <= 128
    const unsigned cy = h0.y + h1.y;
    const int ai = av - 1;
    const int chunk = t >> 3, off = t & 7;
    const float cf[5] = {(float)(cx & 255u), (float)((cx >> 8) & 255u),
                         (float)((cx >> 16) & 255u), (float)(cx >> 24),
                         (float)(cy & 255u)};
#pragma unroll
    for (int ei = 0; ei < 5; ++ei) {
      const int r = ei * 5 + ai;
      Pt[r * 128 + ((chunk ^ (r & 15)) << 3) + off] =
          (unsigned short)f2bf(cf[ei]);
    }
  }
  asm volatile("s_waitcnt lgkmcnt(0)" ::: "memory");
  __builtin_amdgcn_s_barrier();

  // ---- stage 1: Q = adj @ P  (2 col-tiles x 4 k-chunks = 8 MFMA) ----
  s16x8 bP[4][2];
#pragma unroll
  for (int kk = 0; kk < 4; ++kk)
#pragma unroll
    for (int ct = 0; ct < 2; ++ct) {
      const int r = ct * 16 + c;
      bP[kk][ct] =
          *(const s16x8*)&Pt[r * 128 + (((kk * 4 + g) ^ (r & 15)) << 3)];
    }
  // pack adj A-frags (vmcnt(0) lands here; loads issued at T0)
  s16x8 apk[4];
#pragma unroll
  for (int kk = 0; kk < 4; ++kk) {
    unsigned* pu = (unsigned*)&apk[kk];
    pu[0] = pk2(a0[kk][0], a0[kk][1]);
    pu[1] = pk2(a0[kk][2], a0[kk][3]);
    pu[2] = pk2(a1[kk][0], a1[kk][1]);
    pu[3] = pk2(a1[kk][2], a1[kk][3]);
  }
  f32x4 accQ[2] = {{0.f, 0.f, 0.f, 0.f}, {0.f, 0.f, 0.f, 0.f}};
#pragma unroll
  for (int kk = 0; kk < 4; ++kk)
#pragma unroll
    for (int ct = 0; ct < 2; ++ct)
      accQ[ct] = __builtin_amdgcn_mfma_f32_16x16x32_bf16(apk[kk], bP[kk][ct],
                                                         accQ[ct], 0, 0, 0);

  // ---- transpose Q through wave-local LDS (no cross-wave barrier) ----
  unsigned short* qsw = &Qs[w * 16 * 40];
#pragma unroll
  for (int ct = 0; ct < 2; ++ct)
#pragma unroll
    for (int q = 0; q < 4; ++q)
      qsw[(g * 4 + q) * 40 + ct * 16 + c] = (unsigned short)f2bf(accQ[ct][q]);
  const s16x8 aQ = *(const s16x8*)&qsw[c * 40 + g * 8];

  // ---- stage 2: out = Q @ Mtab (8 col-tiles), nontemporal scalar stores ----
  float* ob = out + (size_t)b * 16384 + (size_t)row0 * 128;
#pragma unroll
  for (int mt = 0; mt < 8; ++mt) {
    const s16x8 bM = *(const s16x8*)&Mt[(mt * 16 + c) * 40 + g * 8];
    f32x4 acc2 = {0.f, 0.f, 0.f, 0.f};
    acc2 = __builtin_amdgcn_mfma_f32_16x16x32_bf16(aQ, bM, acc2, 0, 0, 0);
#pragma unroll
    for (int q = 0; q < 4; ++q)
      __builtin_nontemporal_store(acc2[q],
                                  &ob[(g * 4 + q) * 128 + mt * 16 + c]);
  }
}

extern "C" void kernel_launch(void* const* d_in, const int* in_sizes, int n_in,
                              void* d_out, int out_size, void* d_ws,
                              size_t ws_size, hipStream_t stream) {
  // inputs: 0=afm(unused), 1=bfm, 2=a_bfm, 3=adj, 4=adj_w, 5=adj_a
  const int* bfm = (const int*)d_in[1];
  const int* a_bfm = (const int*)d_in[2];
  const float* adj = (const float*)d_in[3];
  const float* adj_w = (const float*)d_in[4];
  const float* adj_a = (const float*)d_in[5];
  float* out = (float*)d_out;

  unsigned short* McT = (unsigned short*)d_ws;   // 128*40 bf16 = 10.24 KB
  uint2* cnt_h = (uint2*)((char*)d_ws + 16384);  // 256*2*128*8B = 512 KB

  hist_mc_kernel<<<dim3(532), dim3(256), 0, stream>>>(bfm, adj_w, adj_a,
                                                      cnt_h, McT);
  skinny_kernel<<<dim3(1024), dim3(128), 0, stream>>>(adj, a_bfm, cnt_h, McT,
                                                      out);
}

// Round 18
// 16.822 us; speedup vs baseline: 1.0553x; 1.0553x over previous
//
#include <hip/hip_runtime.h>

typedef short s16x8 __attribute__((ext_vector_type(8)));
typedef float f32x4 __attribute__((ext_vector_type(4)));
typedef int i32x4 __attribute__((ext_vector_type(4)));

__device__ __forceinline__ short f2bf(float f) {  // RNE f32->bf16
  union { float f; unsigned u; } cv;
  cv.f = f;
  unsigned u = cv.u;
  u = (u + 0x7FFFu + ((u >> 16) & 1u)) >> 16;
  return (short)u;
}
// pack two f32 -> bf16x2 by truncation (low elem = lo)
__device__ __forceinline__ unsigned pk2(float lo, float hi) {
  union { float f; unsigned u; } a, b;
  a.f = lo;
  b.f = hi;
  return (a.u >> 16) | (b.u & 0xFFFF0000u);
}

// ---------------------------------------------------------------------------
// K1: 512 blocks exactly (2/CU, no tail). Block bid = (b = bid>>1, hh).
//  - waves 0/1 additionally compute McT pairs p = bid (+512 if bid<128):
//    e = p%5, m = p/5; lane loads W[e,m,2l..2l+1] + A[a,2l..2l+1] (L2-hot,
//    issued BEFORE the bfm volley), 64-lane shfl reduce, lane 0 writes
//    McT[m*40 + e*5 + a]. Block 511 zeroes pad rows [25,40).
//  - hist of bfm[b] half hh (r16-proven): contiguous nt reads ->
//    cnt_h[(b*2+hh)*128 + j] (uint2, byte-packed, <=64).
// ---------------------------------------------------------------------------
__global__ __launch_bounds__(256, 4) void hist_mc_kernel(
    const int* __restrict__ bfm, const float* __restrict__ adj_w,
    const float* __restrict__ adj_a, uint2* __restrict__ cnt_h,
    unsigned short* __restrict__ McT) {
  __shared__ unsigned red[4][32][4][2];
  const int t = threadIdx.x;
  const int bid = blockIdx.x;
  const int b = bid >> 1, hh = bid & 1;
  const int w = t >> 6, l = t & 63;

  // ---- McT micro-loads FIRST (small, L2-hot; consumed first) ----
  int p = -1;
  float2 wv = make_float2(0.f, 0.f);
  float2 av2[5];
#pragma unroll
  for (int a = 0; a < 5; ++a) av2[a] = make_float2(0.f, 0.f);
  if (w < 2) {
    const int pc = bid + (w << 9);  // wave0: bid, wave1: bid+512
    if (pc < 640) {
      p = pc;
      const int e = pc % 5, m = pc / 5;
      wv = *(const float2*)(adj_w + (size_t)e * 16384 + (size_t)m * 128 + l * 2);
#pragma unroll
      for (int a = 0; a < 5; ++a)
        av2[a] = *(const float2*)(adj_a + a * 128 + l * 2);
    }
  }

  // ---- bfm volley (nt, contiguous 1KB-per-wave) ----
  const i32x4* bp = (const i32x4*)bfm + (size_t)b * 4096 + hh * 2048;
  i32x4 bv[8];
#pragma unroll
  for (int it = 0; it < 8; ++it)
    bv[it] = __builtin_nontemporal_load(&bp[it * 256 + t]);

  // ---- McT compute (vmcnt waits only through its own loads) ----
  if (p >= 0) {
    float acc[5];
#pragma unroll
    for (int a = 0; a < 5; ++a) acc[a] = wv.x * av2[a].x + wv.y * av2[a].y;
#pragma unroll
    for (int d = 1; d < 64; d <<= 1)
#pragma unroll
      for (int a = 0; a < 5; ++a) acc[a] += __shfl_xor(acc[a], d);
    if (l == 0) {
      const int e = p % 5, m = p / 5;
#pragma unroll
      for (int a = 0; a < 5; ++a)
        McT[m * 40 + e * 5 + a] = (unsigned short)f2bf(acc[a]);
    }
  }
  if (bid == 511 && t >= 128) {  // zero pad rows [25,40) once
    const int m = t - 128;
#pragma unroll
    for (int r = 25; r < 40; ++r) McT[m * 40 + r] = 0;
  }

  // ---- histogram (r16-proven) ----
  unsigned pA[4] = {0, 0, 0, 0}, pB[4] = {0, 0, 0, 0};
#pragma unroll
  for (int it = 0; it < 8; ++it) {
#pragma unroll
    for (int jj = 0; jj < 4; ++jj) {
      const int vj = bv[it][jj];
      pA[jj] += (unsigned)(vj == 1) + ((unsigned)(vj == 2) << 8) +
                ((unsigned)(vj == 3) << 16) + ((unsigned)(vj == 4) << 24);
      pB[jj] += (unsigned)(vj == 5);
    }
  }
#pragma unroll
  for (int jj = 0; jj < 4; ++jj) {  // lanes l and l^32 share columns
    pA[jj] += (unsigned)__shfl_xor((int)pA[jj], 32);
    pB[jj] += (unsigned)__shfl_xor((int)pB[jj], 32);
  }
  if (l < 32) {
#pragma unroll
    for (int jj = 0; jj < 4; ++jj) {
      red[w][l][jj][0] = pA[jj];
      red[w][l][jj][1] = pB[jj];
    }
  }
  __syncthreads();
  if (t < 128) {
    unsigned A = 0, B = 0;
    const int cc = t >> 2, jj = t & 3;
#pragma unroll
    for (int w2 = 0; w2 < 4; ++w2) {
      A += red[w2][cc][jj][0];
      B += red[w2][cc][jj][1];
    }
    cnt_h[(b * 2 + hh) * 128 + t] = make_uint2(A, B);  // bytes <= 64
  }
}

// ---------------------------------------------------------------------------
// K2 (r16-proven, verbatim): out[b, h*64 .. +64, :] = (adj@P) @ McT, two
// skinny MFMA stages. 512 blocks (b, half) x 256 threads, ~23 KB LDS.
// ---------------------------------------------------------------------------
__global__ __launch_bounds__(256, 2) void skinny_kernel(
    const float* __restrict__ adj, const int* __restrict__ a_bfm,
    const uint2* __restrict__ cnt_h, const unsigned short* __restrict__ McT,
    float* __restrict__ out) {
  __shared__ __align__(16) unsigned short Pt[32 * 128];     // 8 KB, XOR-swz
  __shared__ __align__(16) unsigned short Mt[128 * 40];     // 10 KB
  __shared__ __align__(16) unsigned short Qs[4 * 16 * 40];  // 5 KB
  const int bh = blockIdx.x, b = bh >> 1, hh = bh & 1;
  const int t = threadIdx.x, w = t >> 6, l = t & 63, g = l >> 4, c = l & 15;
  const int row0 = hh * 64 + w * 16;

  // ---- T0: small loads first (consumed first), adj last (consumed last) ----
  uint2 h0 = make_uint2(0u, 0u), h1 = make_uint2(0u, 0u);
  int av = 0;
  if (t < 128) {
    h0 = cnt_h[(b * 2 + 0) * 128 + t];
    h1 = cnt_h[(b * 2 + 1) * 128 + t];
    av = a_bfm[b * 128 + t];
  }
  s16x8 mst0 = *(const s16x8*)&McT[t * 8];
  s16x8 mst1 = *(const s16x8*)&McT[(256 + t) * 8];
  s16x8 mst2 = {0, 0, 0, 0, 0, 0, 0, 0};
  if (t < 128) mst2 = *(const s16x8*)&McT[(512 + t) * 8];
  const float* arow = adj + (size_t)b * 16384 + (size_t)(row0 + c) * 128;
  f32x4 a0[4], a1[4];
#pragma unroll
  for (int kk = 0; kk < 4; ++kk) {
    a0[kk] = __builtin_nontemporal_load((const f32x4*)(arow + kk * 32 + g * 8));
    a1[kk] =
        __builtin_nontemporal_load((const f32x4*)(arow + kk * 32 + g * 8 + 4));
  }

  // ---- zero Pt; stage Mt (vmcnt waits only to mst; adj stays queued) ----
  ((uint4*)Pt)[t] = make_uint4(0u, 0u, 0u, 0u);
  ((uint4*)Pt)[256 + t] = make_uint4(0u, 0u, 0u, 0u);
  *(s16x8*)&Mt[t * 8] = mst0;
  *(s16x8*)&Mt[(256 + t) * 8] = mst1;
  if (t < 128) *(s16x8*)&Mt[(512 + t) * 8] = mst2;
  asm volatile("s_waitcnt lgkmcnt(0)" ::: "memory");
  __builtin_amdgcn_s_barrier();

  // ---- scatter P^T: Pt[r][j=t] = cnt_e(j), r=(e-1)*5+ai, XOR-swz chunks ----
  if (t < 128 && av > 0) {
    const unsigned cx = h0.x + h1.x;  // byte-packed add, bytes <= 128
    const unsigned cy = h0.y + h1.y;
    const int ai = av - 1;
    const int chunk = t >> 3, off = t & 7;
    const float cf[5] = {(float)(cx & 255u), (float)((cx >> 8) & 255u),
                         (float)((cx >> 16) & 255u), (float)(cx >> 24),
                         (float)(cy & 255u)};
#pragma unroll
    for (int ei = 0; ei < 5; ++ei) {
      const int r = ei * 5 + ai;
      Pt[r * 128 + ((chunk ^ (r & 15)) << 3) + off] =
          (unsigned short)f2bf(cf[ei]);
    }
  }
  asm volatile("s_waitcnt lgkmcnt(0)" ::: "memory");
  __builtin_amdgcn_s_barrier();

  // ---- stage 1: Q = adj @ P  (2 col-tiles x 4 k-chunks = 8 MFMA) ----
  s16x8 bP[4][2];
#pragma unroll
  for (int kk = 0; kk < 4; ++kk)
#pragma unroll
    for (int ct = 0; ct < 2; ++ct) {
      const int r = ct * 16 + c;
      bP[kk][ct] = *(const s16x8*)&Pt[r * 128 + (((kk * 4 + g) ^ (r & 15)) << 3)];
    }
  // pack adj A-frags (vmcnt(0) lands here; loads issued at T0, well covered)
  s16x8 apk[4];
#pragma unroll
  for (int kk = 0; kk < 4; ++kk) {
    unsigned* pu = (unsigned*)&apk[kk];
    pu[0] = pk2(a0[kk][0], a0[kk][1]);
    pu[1] = pk2(a0[kk][2], a0[kk][3]);
    pu[2] = pk2(a1[kk][0], a1[kk][1]);
    pu[3] = pk2(a1[kk][2], a1[kk][3]);
  }
  f32x4 accQ[2] = {{0.f, 0.f, 0.f, 0.f}, {0.f, 0.f, 0.f, 0.f}};
#pragma unroll
  for (int kk = 0; kk < 4; ++kk)
#pragma unroll
    for (int ct = 0; ct < 2; ++ct)
      accQ[ct] = __builtin_amdgcn_mfma_f32_16x16x32_bf16(apk[kk], bP[kk][ct],
                                                         accQ[ct], 0, 0, 0);

  // ---- transpose Q through wave-local LDS (no cross-wave barrier) ----
  unsigned short* qsw = &Qs[w * 16 * 40];
#pragma unroll
  for (int ct = 0; ct < 2; ++ct)
#pragma unroll
    for (int q = 0; q < 4; ++q)
      qsw[(g * 4 + q) * 40 + ct * 16 + c] = (unsigned short)f2bf(accQ[ct][q]);
  const s16x8 aQ = *(const s16x8*)&qsw[c * 40 + g * 8];

  // ---- stage 2: out = Q @ Mtab (8 col-tiles), nontemporal scalar stores ----
  float* ob = out + (size_t)b * 16384 + (size_t)row0 * 128;
#pragma unroll
  for (int mt = 0; mt < 8; ++mt) {
    const s16x8 bM = *(const s16x8*)&Mt[(mt * 16 + c) * 40 + g * 8];
    f32x4 acc2 = {0.f, 0.f, 0.f, 0.f};
    acc2 = __builtin_amdgcn_mfma_f32_16x16x32_bf16(aQ, bM, acc2, 0, 0, 0);
#pragma unroll
    for (int q = 0; q < 4; ++q)
      __builtin_nontemporal_store(acc2[q],
                                  &ob[(g * 4 + q) * 128 + mt * 16 + c]);
  }
}

extern "C" void kernel_launch(void* const* d_in, const int* in_sizes, int n_in,
                              void* d_out, int out_size, void* d_ws,
                              size_t ws_size, hipStream_t stream) {
  // inputs: 0=afm(unused), 1=bfm, 2=a_bfm, 3=adj, 4=adj_w, 5=adj_a
  const int* bfm = (const int*)d_in[1];
  const int* a_bfm = (const int*)d_in[2];
  const float* adj = (const float*)d_in[3];
  const float* adj_w = (const float*)d_in[4];
  const float* adj_a = (const float*)d_in[5];
  float* out = (float*)d_out;

  unsigned short* McT = (unsigned short*)d_ws;   // 128*40 bf16 = 10.24 KB
  uint2* cnt_h = (uint2*)((char*)d_ws + 16384);  // 256*2*128*8B = 512 KB

  hist_mc_kernel<<<dim3(512), dim3(256), 0, stream>>>(bfm, adj_w, adj_a,
                                                      cnt_h, McT);
  skinny_kernel<<<dim3(512), dim3(256), 0, stream>>>(adj, a_bfm, cnt_h, McT,
                                                     out);
}